// Round 7
// baseline (1457.356 us; speedup 1.0000x reference)
//
#include <hip/hip_runtime.h>

#define NN 100000      // nodes
#define NE 1600000     // edges
#define NF 128         // in features
#define NH 64          // hidden
#define NC 40          // classes

#define BKN 128                      // nodes per bucket
#define NBK ((NN + BKN - 1) / BKN)   // 782 buckets
#define CH  4096                     // edges per scatter block
#define NCHB ((NE + CH - 1) / CH)    // 391 scatter blocks
#define CAPB 2560                    // slots per bucket region (mean 2046, sigma 45)

__device__ __forceinline__ unsigned short f2bf(float f) {
    unsigned int u = __builtin_bit_cast(unsigned int, f);
    u += 0x7FFFu + ((u >> 16) & 1u);          // round-to-nearest-even
    return (unsigned short)(u >> 16);
}
__device__ __forceinline__ float bf2f(unsigned short b) {
    unsigned int u = ((unsigned int)b) << 16;
    return __builtin_bit_cast(float, u);
}

// ---------------- coarse bucket CSR (fixed-capacity regions) ----------------

// block bins CH edges by bucket in LDS, claims space in each bucket's fixed
// region via atomicAdd(gcnt), writes bucket-sorted packed edges as runs.
// enc = (col & 127) << 24 | row      (row < 2^17)
__global__ __launch_bounds__(256) void bucket_scatter(const int* __restrict__ row,
                                                      const int* __restrict__ col,
                                                      int* __restrict__ gcnt,
                                                      unsigned int* __restrict__ encs) {
    __shared__ int h[NBK];
    __shared__ int loff[NBK];
    __shared__ int cur[NBK];
    __shared__ int gbase[NBK];
    __shared__ unsigned int stage[CH];
    __shared__ unsigned short sbkt[CH];
    int tid = threadIdx.x;
    for (int i = tid; i < NBK; i += 256) h[i] = 0;
    __syncthreads();
    int e0 = blockIdx.x * CH;
    int nval = NE - e0; if (nval > CH) nval = CH;
    int c[16];
    #pragma unroll
    for (int i = 0; i < 16; ++i) {
        int e = e0 + i * 256 + tid;
        c[i] = (e < NE) ? col[e] : -1;
        if (c[i] >= 0) atomicAdd(&h[c[i] >> 7], 1);
    }
    __syncthreads();
    // exclusive scan of h[0..NBK) by wave 0 (13 elems/lane, 64*13=832 >= 782)
    if (tid < 64) {
        int lane = tid, base = lane * 13;
        int pre[13]; int sum = 0;
        #pragma unroll
        for (int j = 0; j < 13; ++j) {
            int idx = base + j;
            int x = (idx < NBK) ? h[idx] : 0;
            pre[j] = sum; sum += x;
        }
        int run = sum;
        #pragma unroll
        for (int d = 1; d < 64; d <<= 1) {
            int n = __shfl_up(run, d, 64);
            if (lane >= d) run += n;
        }
        int lex = run - sum;
        #pragma unroll
        for (int j = 0; j < 13; ++j) {
            int idx = base + j;
            if (idx < NBK) { loff[idx] = lex + pre[j]; cur[idx] = lex + pre[j]; }
        }
    }
    __syncthreads();
    // claim global space per bucket
    for (int i = tid; i < NBK; i += 256) {
        int cnt = h[i];
        gbase[i] = cnt ? atomicAdd(&gcnt[i], cnt) : 0;
    }
    __syncthreads();
    // rank + stage bucket-sorted
    #pragma unroll
    for (int i = 0; i < 16; ++i) {
        int e = e0 + i * 256 + tid;
        if (e < NE) {
            int cc = c[i], b = cc >> 7;
            int r = atomicAdd(&cur[b], 1);
            stage[r] = ((unsigned int)(cc & 127) << 24) | (unsigned int)row[e];
            sbkt[r] = (unsigned short)b;
        }
    }
    __syncthreads();
    // linear write-out: consecutive slots of a bucket -> consecutive global addrs
    for (int s = tid; s < nval; s += 256) {
        int b = sbkt[s];
        encs[(size_t)b * CAPB + gbase[b] + (s - loff[b])] = stage[s];
    }
}

// exact per-node degree from bucket segment -> dinv
__global__ __launch_bounds__(BKN) void deg_dinv(const unsigned int* __restrict__ encs,
                                                const int* __restrict__ gcnt,
                                                float* __restrict__ dinv) {
    __shared__ int h[BKN];
    int b = blockIdx.x, tid = threadIdx.x;
    h[tid] = 0;
    __syncthreads();
    int m = gcnt[b];
    const unsigned int* seg = encs + (size_t)b * CAPB;
    for (int s = tid; s < m; s += BKN)
        atomicAdd(&h[seg[s] >> 24], 1);
    __syncthreads();
    int g = b * BKN + tid;
    if (g < NN) dinv[g] = rsqrtf((float)(h[tid] + 1));   // +1 self loop
}

// ---------------- tiled fp32 GEMM ----------------
// Block: 64 rows x N cols. 256 threads as 16x16; each thread owns 4 rows x 4 cols.
// EPI==0: hsb[r][c] = bf16(acc * aux[r])   (aux = dinv, pre-scaled bf16 table)
// EPI==1: outf[r][c] = acc + aux[c]        (aux = bias, classifier, fp32)
template <int K, int N, int EPI>
__global__ __launch_bounds__(256) void gemm_tiled(const float* __restrict__ X,
                                                  const float* __restrict__ W,
                                                  const float* __restrict__ aux,
                                                  float* __restrict__ outf,
                                                  unsigned short* __restrict__ hsb) {
    constexpr int KT  = 64;
    constexpr int KTP = KT + 4;
    __shared__ float Xl[64 * KTP];
    __shared__ float Wl[KT * N + 64];
    int tid = threadIdx.x;
    int tr = tid >> 4, tc = tid & 15;
    int rbase = blockIdx.x * 64;
    float4 acc[4] = {};

    for (int kt = 0; kt < K; kt += KT) {
        int fid = tid;
        #pragma unroll
        for (int p = 0; p < 4; ++p, fid += 256) {
            int m = fid >> 4, k4 = fid & 15;
            int rr = rbase + m; if (rr >= NN) rr = NN - 1;
            float4 v = *(const float4*)(X + (size_t)rr * K + kt + k4 * 4);
            *(float4*)(Xl + m * KTP + k4 * 4) = v;
        }
        constexpr int NW4 = KT * N / 4;
        for (int f = tid; f < NW4; f += 256)
            ((float4*)Wl)[f] = *((const float4*)(W + (size_t)kt * N) + f);
        __syncthreads();

        #pragma unroll 2
        for (int k4 = 0; k4 < KT / 4; ++k4) {
            float4 xa[4], wa[4];
            #pragma unroll
            for (int i = 0; i < 4; ++i)
                xa[i] = *(const float4*)(Xl + (tr * 4 + i) * KTP + k4 * 4);
            #pragma unroll
            for (int j = 0; j < 4; ++j)
                wa[j] = *(const float4*)(Wl + (k4 * 4 + j) * N + tc * 4);
            #pragma unroll
            for (int i = 0; i < 4; ++i) {
                acc[i].x = fmaf(xa[i].x, wa[0].x, acc[i].x);
                acc[i].y = fmaf(xa[i].x, wa[0].y, acc[i].y);
                acc[i].z = fmaf(xa[i].x, wa[0].z, acc[i].z);
                acc[i].w = fmaf(xa[i].x, wa[0].w, acc[i].w);
                acc[i].x = fmaf(xa[i].y, wa[1].x, acc[i].x);
                acc[i].y = fmaf(xa[i].y, wa[1].y, acc[i].y);
                acc[i].z = fmaf(xa[i].y, wa[1].z, acc[i].z);
                acc[i].w = fmaf(xa[i].y, wa[1].w, acc[i].w);
                acc[i].x = fmaf(xa[i].z, wa[2].x, acc[i].x);
                acc[i].y = fmaf(xa[i].z, wa[2].y, acc[i].y);
                acc[i].z = fmaf(xa[i].z, wa[2].z, acc[i].z);
                acc[i].w = fmaf(xa[i].z, wa[2].w, acc[i].w);
                acc[i].x = fmaf(xa[i].w, wa[3].x, acc[i].x);
                acc[i].y = fmaf(xa[i].w, wa[3].y, acc[i].y);
                acc[i].z = fmaf(xa[i].w, wa[3].z, acc[i].z);
                acc[i].w = fmaf(xa[i].w, wa[3].w, acc[i].w);
            }
        }
        __syncthreads();
    }

    if (EPI == 0) {
        #pragma unroll
        for (int i = 0; i < 4; ++i) {
            int r = rbase + tr * 4 + i;
            if (r < NN) {
                float d = aux[r];
                ushort4 o;
                o.x = f2bf(acc[i].x * d);
                o.y = f2bf(acc[i].y * d);
                o.z = f2bf(acc[i].z * d);
                o.w = f2bf(acc[i].w * d);
                *(ushort4*)(hsb + (size_t)r * N + tc * 4) = o;
            }
        }
    } else {
        if (tc * 4 < N) {
            float4 b = *(const float4*)(aux + tc * 4);
            #pragma unroll
            for (int i = 0; i < 4; ++i) {
                int r = rbase + tr * 4 + i;
                if (r < NN) {
                    float4 v = acc[i];
                    v.x += b.x; v.y += b.y; v.z += b.z; v.w += b.w;
                    *(float4*)(outf + (size_t)r * N + tc * 4) = v;
                }
            }
        }
    }
}

// ---------------- edge-parallel aggregation with LDS accumulators ----------------
// Block = 128-node bucket, 512 threads = 32 subgroups of 16 lanes.
// LDS acc layout [j][node][slot] (j = feature%4, slot = feature/4 = lane sl):
// bank = (node*16 + sl) & 31 -> 1 lane/bank per subgroup, ~2-way across wave (free).
// All subgroups walk the packed edge list in lockstep (zero divergence), 4-deep
// unroll = 16 gathers in flight per wave; ds_add_f32 accumulate; fused finalize.
// out[g] = relu(dinv[g] * (hs[g] + sum_{r in in(g)} hs[r]) + bias)   [fp32 out]
__global__ __launch_bounds__(512) void aggregate_edges(const unsigned short* __restrict__ hs,
                                                       const unsigned int* __restrict__ encs,
                                                       const int* __restrict__ gcnt,
                                                       const float* __restrict__ dinv,
                                                       const float* __restrict__ bias,
                                                       float* __restrict__ out) {
    __shared__ float acc[4 * BKN * 16];              // 32 KB
    int b = blockIdx.x, tid = threadIdx.x;
    const ushort4* hs4 = (const ushort4*)hs;         // row = 16 x ushort4 (128 B)

    // init with self-loop row
    for (int i = tid; i < BKN * 16; i += 512) {
        int n = i >> 4, q = i & 15;
        int g = b * BKN + n;
        int p = n * 16 + q;
        if (g < NN) {
            ushort4 v = hs4[(size_t)g * 16 + q];
            acc[p]                = bf2f(v.x);
            acc[p + BKN * 16]     = bf2f(v.y);
            acc[p + 2 * BKN * 16] = bf2f(v.z);
            acc[p + 3 * BKN * 16] = bf2f(v.w);
        }
    }
    __syncthreads();

    int m = gcnt[b];
    const unsigned int* seg = encs + (size_t)b * CAPB;
    int sgid = tid >> 4, sl = tid & 15;
    int e = sgid;
    for (; e + 96 < m; e += 128) {
        unsigned int e0 = seg[e], e1 = seg[e + 32], e2 = seg[e + 64], e3 = seg[e + 96];
        ushort4 v0 = hs4[(size_t)(e0 & 0xFFFFFFu) * 16 + sl];
        ushort4 v1 = hs4[(size_t)(e1 & 0xFFFFFFu) * 16 + sl];
        ushort4 v2 = hs4[(size_t)(e2 & 0xFFFFFFu) * 16 + sl];
        ushort4 v3 = hs4[(size_t)(e3 & 0xFFFFFFu) * 16 + sl];
        int p0 = (int)(e0 >> 24) * 16 + sl;
        int p1 = (int)(e1 >> 24) * 16 + sl;
        int p2 = (int)(e2 >> 24) * 16 + sl;
        int p3 = (int)(e3 >> 24) * 16 + sl;
        atomicAdd(&acc[p0], bf2f(v0.x));
        atomicAdd(&acc[p0 + BKN * 16], bf2f(v0.y));
        atomicAdd(&acc[p0 + 2 * BKN * 16], bf2f(v0.z));
        atomicAdd(&acc[p0 + 3 * BKN * 16], bf2f(v0.w));
        atomicAdd(&acc[p1], bf2f(v1.x));
        atomicAdd(&acc[p1 + BKN * 16], bf2f(v1.y));
        atomicAdd(&acc[p1 + 2 * BKN * 16], bf2f(v1.z));
        atomicAdd(&acc[p1 + 3 * BKN * 16], bf2f(v1.w));
        atomicAdd(&acc[p2], bf2f(v2.x));
        atomicAdd(&acc[p2 + BKN * 16], bf2f(v2.y));
        atomicAdd(&acc[p2 + 2 * BKN * 16], bf2f(v2.z));
        atomicAdd(&acc[p2 + 3 * BKN * 16], bf2f(v2.w));
        atomicAdd(&acc[p3], bf2f(v3.x));
        atomicAdd(&acc[p3 + BKN * 16], bf2f(v3.y));
        atomicAdd(&acc[p3 + 2 * BKN * 16], bf2f(v3.z));
        atomicAdd(&acc[p3 + 3 * BKN * 16], bf2f(v3.w));
    }
    for (; e < m; e += 32) {
        unsigned int ee = seg[e];
        ushort4 v = hs4[(size_t)(ee & 0xFFFFFFu) * 16 + sl];
        int p = (int)(ee >> 24) * 16 + sl;
        atomicAdd(&acc[p], bf2f(v.x));
        atomicAdd(&acc[p + BKN * 16], bf2f(v.y));
        atomicAdd(&acc[p + 2 * BKN * 16], bf2f(v.z));
        atomicAdd(&acc[p + 3 * BKN * 16], bf2f(v.w));
    }
    __syncthreads();

    // finalize: scale + bias + relu, coalesced float4 stores
    for (int i = tid; i < BKN * 16; i += 512) {
        int n = i >> 4, q = i & 15;
        int g = b * BKN + n;
        if (g < NN) {
            int p = n * 16 + q;
            float d = dinv[g];
            float4 bb = *(const float4*)(bias + q * 4);
            float4 o;
            o.x = fmaxf(fmaf(acc[p], d, bb.x), 0.f);
            o.y = fmaxf(fmaf(acc[p + BKN * 16], d, bb.y), 0.f);
            o.z = fmaxf(fmaf(acc[p + 2 * BKN * 16], d, bb.z), 0.f);
            o.w = fmaxf(fmaf(acc[p + 3 * BKN * 16], d, bb.w), 0.f);
            ((float4*)out)[(size_t)g * 16 + q] = o;
        }
    }
}

// ---------------- launch ----------------

extern "C" void kernel_launch(void* const* d_in, const int* in_sizes, int n_in,
                              void* d_out, int out_size, void* d_ws, size_t ws_size,
                              hipStream_t stream) {
    const float* x  = (const float*)d_in[0];
    const int* ei   = (const int*)d_in[1];      // [2, NE]
    const int* row  = ei;
    const int* col  = ei + NE;
    const float* W1 = (const float*)d_in[2];
    const float* b1 = (const float*)d_in[3];
    const float* W2 = (const float*)d_in[4];
    const float* b2 = (const float*)d_in[5];
    const float* Wc = (const float*)d_in[6];
    const float* bc = (const float*)d_in[7];
    float* out = (float*)d_out;

    char* ws = (char*)d_ws;
    size_t off = 0;
    auto alloc = [&](size_t bytes) {
        void* p = ws + off;
        off = (off + bytes + 255) & ~(size_t)255;
        return p;
    };
    int*   gcnt = (int*)alloc((size_t)NBK * 4);
    float* dinv = (float*)alloc((size_t)NN * 4);
    unsigned int* encs = (unsigned int*)alloc((size_t)NBK * CAPB * 4);   // 8 MB
    unsigned short* hsb = (unsigned short*)alloc((size_t)NN * NH * 2);   // bf16 table
    float* bufB = (float*)alloc((size_t)NN * NH * 4);

    const int GB = (NN + 63) / 64;               // 1563

    hipMemsetAsync(gcnt, 0, (size_t)NBK * 4, stream);
    bucket_scatter<<<NCHB, 256, 0, stream>>>(row, col, gcnt, encs);
    deg_dinv<<<NBK, BKN, 0, stream>>>(encs, gcnt, dinv);

    // layer 1: hsb = bf16((x @ W1) * dinv) ; h1 = relu(dinv * agg + b1)
    gemm_tiled<NF, NH, 0><<<GB, 256, 0, stream>>>(x, W1, dinv, nullptr, hsb);
    aggregate_edges<<<NBK, 512, 0, stream>>>(hsb, encs, gcnt, dinv, b1, bufB);
    // layer 2
    gemm_tiled<NH, NH, 0><<<GB, 256, 0, stream>>>(bufB, W2, dinv, nullptr, hsb);
    aggregate_edges<<<NBK, 512, 0, stream>>>(hsb, encs, gcnt, dinv, b2, bufB);
    // classifier
    gemm_tiled<NH, NC, 1><<<GB, 256, 0, stream>>>(bufB, Wc, bc, out, nullptr);
}

// Round 8
// 173.833 us; speedup vs baseline: 8.3837x; 8.3837x over previous
//
#include <hip/hip_runtime.h>

#define NN 100000      // nodes
#define NE 1600000     // edges
#define NF 128         // in features
#define NH 64          // hidden
#define NC 40          // classes

#define BKN 128                      // nodes per bucket
#define NBK ((NN + BKN - 1) / BKN)   // 782 buckets
#define CH  4096                     // edges per scatter block
#define NCHB ((NE + CH - 1) / CH)    // 391 scatter blocks
#define CAPB 2560                    // slots per bucket region (mean 2046, sigma 45)
#define OFFS (BKN + 1)
#define HCAP 1408                    // max edges per 64-node half-bucket (mean 1023, +12 sigma)

__device__ __forceinline__ unsigned short f2bf(float f) {
    unsigned int u = __builtin_bit_cast(unsigned int, f);
    u += 0x7FFFu + ((u >> 16) & 1u);          // round-to-nearest-even
    return (unsigned short)(u >> 16);
}
__device__ __forceinline__ float bf2f(unsigned short b) {
    unsigned int u = ((unsigned int)b) << 16;
    return __builtin_bit_cast(float, u);
}
__device__ __forceinline__ void bfacc(float4& a, ushort4 v) {
    a.x += bf2f(v.x); a.y += bf2f(v.y); a.z += bf2f(v.z); a.w += bf2f(v.w);
}

// ---------------- coarse bucket CSR (fixed-capacity regions) ----------------

// block bins CH edges by bucket in LDS, claims space in each bucket's fixed
// region via atomicAdd(gcnt), writes bucket-sorted packed edges as runs.
// enc = (col & 127) << 24 | row      (row < 2^17)
__global__ __launch_bounds__(256) void bucket_scatter(const int* __restrict__ row,
                                                      const int* __restrict__ col,
                                                      int* __restrict__ gcnt,
                                                      unsigned int* __restrict__ encs) {
    __shared__ int h[NBK];
    __shared__ int loff[NBK];
    __shared__ int cur[NBK];
    __shared__ int gbase[NBK];
    __shared__ unsigned int stage[CH];
    __shared__ unsigned short sbkt[CH];
    int tid = threadIdx.x;
    for (int i = tid; i < NBK; i += 256) h[i] = 0;
    __syncthreads();
    int e0 = blockIdx.x * CH;
    int nval = NE - e0; if (nval > CH) nval = CH;
    int c[16];
    #pragma unroll
    for (int i = 0; i < 16; ++i) {
        int e = e0 + i * 256 + tid;
        c[i] = (e < NE) ? col[e] : -1;
        if (c[i] >= 0) atomicAdd(&h[c[i] >> 7], 1);
    }
    __syncthreads();
    // exclusive scan of h[0..NBK) by wave 0 (13 elems/lane, 64*13=832 >= 782)
    if (tid < 64) {
        int lane = tid, base = lane * 13;
        int pre[13]; int sum = 0;
        #pragma unroll
        for (int j = 0; j < 13; ++j) {
            int idx = base + j;
            int x = (idx < NBK) ? h[idx] : 0;
            pre[j] = sum; sum += x;
        }
        int run = sum;
        #pragma unroll
        for (int d = 1; d < 64; d <<= 1) {
            int n = __shfl_up(run, d, 64);
            if (lane >= d) run += n;
        }
        int lex = run - sum;
        #pragma unroll
        for (int j = 0; j < 13; ++j) {
            int idx = base + j;
            if (idx < NBK) { loff[idx] = lex + pre[j]; cur[idx] = lex + pre[j]; }
        }
    }
    __syncthreads();
    // claim global space per bucket
    for (int i = tid; i < NBK; i += 256) {
        int cnt = h[i];
        gbase[i] = cnt ? atomicAdd(&gcnt[i], cnt) : 0;
    }
    __syncthreads();
    // rank + stage bucket-sorted
    #pragma unroll
    for (int i = 0; i < 16; ++i) {
        int e = e0 + i * 256 + tid;
        if (e < NE) {
            int cc = c[i], b = cc >> 7;
            int r = atomicAdd(&cur[b], 1);
            stage[r] = ((unsigned int)(cc & 127) << 24) | (unsigned int)row[e];
            sbkt[r] = (unsigned short)b;
        }
    }
    __syncthreads();
    // linear write-out: consecutive slots of a bucket -> consecutive global addrs
    for (int s = tid; s < nval; s += 256) {
        int b = sbkt[s];
        encs[(size_t)b * CAPB + gbase[b] + (s - loff[b])] = stage[s];
    }
}

// ---------------- csr_sort: node-sort each bucket IN PLACE, emit off + dinv ----------------
// After this, encs[b*CAPB ..] holds plain row indices, node-sorted; offg[b*OFFS+i]
// gives each node's segment. Runs once, reused by both aggregations.
__global__ __launch_bounds__(256) void csr_sort(unsigned int* __restrict__ encs,
                                                const int* __restrict__ gcnt,
                                                int* __restrict__ offg,
                                                float* __restrict__ dinv) {
    __shared__ unsigned int sseg[CAPB];
    __shared__ int h[BKN];
    __shared__ int off[OFFS];
    __shared__ int cur[BKN];
    int b = blockIdx.x, tid = threadIdx.x;
    if (tid < BKN) h[tid] = 0;
    __syncthreads();
    int m = gcnt[b];
    unsigned int* seg = encs + (size_t)b * CAPB;
    for (int s = tid; s < m; s += 256) {
        unsigned int e = seg[s];
        sseg[s] = e;
        atomicAdd(&h[e >> 24], 1);
    }
    __syncthreads();
    // dinv from exact degree
    if (tid < BKN) {
        int g = b * BKN + tid;
        if (g < NN) dinv[g] = rsqrtf((float)(h[tid] + 1));   // +1 self loop
    }
    // exclusive scan of h (wave 0, 2 elems/lane)
    if (tid < 64) {
        int lane = tid;
        int x0 = h[lane * 2], x1 = h[lane * 2 + 1];
        int sum = x0 + x1, run = sum;
        #pragma unroll
        for (int d = 1; d < 64; d <<= 1) {
            int n = __shfl_up(run, d, 64);
            if (lane >= d) run += n;
        }
        int ex = run - sum;
        off[lane * 2] = ex;          cur[lane * 2] = ex;
        off[lane * 2 + 1] = ex + x0; cur[lane * 2 + 1] = ex + x0;
        if (lane == 63) off[BKN] = run;
    }
    __syncthreads();
    // rank from LDS copy, write node-sorted row indices back in place
    for (int s = tid; s < m; s += 256) {
        unsigned int e = sseg[s];
        int n = e >> 24;
        int r = atomicAdd(&cur[n], 1);
        seg[r] = e & 0xFFFFFFu;
    }
    if (tid < OFFS) offg[b * OFFS + tid] = off[tid];
}

// ---------------- tiled fp32 GEMM ----------------
// Block: 64 rows x N cols. 256 threads as 16x16; each thread owns 4 rows x 4 cols.
// EPI==0: hsb[r][c] = bf16(acc * aux[r])   (aux = dinv, pre-scaled bf16 table)
// EPI==1: outf[r][c] = acc + aux[c]        (aux = bias, classifier, fp32)
template <int K, int N, int EPI>
__global__ __launch_bounds__(256) void gemm_tiled(const float* __restrict__ X,
                                                  const float* __restrict__ W,
                                                  const float* __restrict__ aux,
                                                  float* __restrict__ outf,
                                                  unsigned short* __restrict__ hsb) {
    constexpr int KT  = 64;
    constexpr int KTP = KT + 4;
    __shared__ float Xl[64 * KTP];
    __shared__ float Wl[KT * N + 64];
    int tid = threadIdx.x;
    int tr = tid >> 4, tc = tid & 15;
    int rbase = blockIdx.x * 64;
    float4 acc[4] = {};

    for (int kt = 0; kt < K; kt += KT) {
        int fid = tid;
        #pragma unroll
        for (int p = 0; p < 4; ++p, fid += 256) {
            int m = fid >> 4, k4 = fid & 15;
            int rr = rbase + m; if (rr >= NN) rr = NN - 1;
            float4 v = *(const float4*)(X + (size_t)rr * K + kt + k4 * 4);
            *(float4*)(Xl + m * KTP + k4 * 4) = v;
        }
        constexpr int NW4 = KT * N / 4;
        for (int f = tid; f < NW4; f += 256)
            ((float4*)Wl)[f] = *((const float4*)(W + (size_t)kt * N) + f);
        __syncthreads();

        #pragma unroll 2
        for (int k4 = 0; k4 < KT / 4; ++k4) {
            float4 xa[4], wa[4];
            #pragma unroll
            for (int i = 0; i < 4; ++i)
                xa[i] = *(const float4*)(Xl + (tr * 4 + i) * KTP + k4 * 4);
            #pragma unroll
            for (int j = 0; j < 4; ++j)
                wa[j] = *(const float4*)(Wl + (k4 * 4 + j) * N + tc * 4);
            #pragma unroll
            for (int i = 0; i < 4; ++i) {
                acc[i].x = fmaf(xa[i].x, wa[0].x, acc[i].x);
                acc[i].y = fmaf(xa[i].x, wa[0].y, acc[i].y);
                acc[i].z = fmaf(xa[i].x, wa[0].z, acc[i].z);
                acc[i].w = fmaf(xa[i].x, wa[0].w, acc[i].w);
                acc[i].x = fmaf(xa[i].y, wa[1].x, acc[i].x);
                acc[i].y = fmaf(xa[i].y, wa[1].y, acc[i].y);
                acc[i].z = fmaf(xa[i].y, wa[1].z, acc[i].z);
                acc[i].w = fmaf(xa[i].y, wa[1].w, acc[i].w);
                acc[i].x = fmaf(xa[i].z, wa[2].x, acc[i].x);
                acc[i].y = fmaf(xa[i].z, wa[2].y, acc[i].y);
                acc[i].z = fmaf(xa[i].z, wa[2].z, acc[i].z);
                acc[i].w = fmaf(xa[i].z, wa[2].w, acc[i].w);
                acc[i].x = fmaf(xa[i].w, wa[3].x, acc[i].x);
                acc[i].y = fmaf(xa[i].w, wa[3].y, acc[i].y);
                acc[i].z = fmaf(xa[i].w, wa[3].z, acc[i].z);
                acc[i].w = fmaf(xa[i].w, wa[3].w, acc[i].w);
            }
        }
        __syncthreads();
    }

    if (EPI == 0) {
        #pragma unroll
        for (int i = 0; i < 4; ++i) {
            int r = rbase + tr * 4 + i;
            if (r < NN) {
                float d = aux[r];
                ushort4 o;
                o.x = f2bf(acc[i].x * d);
                o.y = f2bf(acc[i].y * d);
                o.z = f2bf(acc[i].z * d);
                o.w = f2bf(acc[i].w * d);
                *(ushort4*)(hsb + (size_t)r * N + tc * 4) = o;
            }
        }
    } else {
        if (tc * 4 < N) {
            float4 b = *(const float4*)(aux + tc * 4);
            #pragma unroll
            for (int i = 0; i < 4; ++i) {
                int r = rbase + tr * 4 + i;
                if (r < NN) {
                    float4 v = acc[i];
                    v.x += b.x; v.y += b.y; v.z += b.z; v.w += b.w;
                    *(float4*)(outf + (size_t)r * N + tc * 4) = v;
                }
            }
        }
    }
}

// ---------------- aggregation: subgroup-per-node bf16 gather, LDS-staged indices ----------------
// Block = HALF bucket (64 nodes), 256 threads = 4 waves x 4 subgroups of 16 lanes.
// Edge indices for the half staged in LDS (one coalesced pass) so the gather's
// only global access is the row load; unroll 8 keeps 8 gathers in flight.
// out[g] = relu(dinv[g] * (hs[g] + sum_{r in in(g)} hs[r]) + bias)   [fp32 out]
__global__ __launch_bounds__(256) void aggregate_bucket(const unsigned short* __restrict__ hs,
                                                        const int* __restrict__ srow,
                                                        const int* __restrict__ offg,
                                                        const float* __restrict__ dinv,
                                                        const float* __restrict__ bias,
                                                        float* __restrict__ out) {
    __shared__ int off[65];
    __shared__ int sidx[HCAP];
    int b = blockIdx.x >> 1, half = blockIdx.x & 1;
    int tid = threadIdx.x;
    if (tid < 65) off[tid] = offg[b * OFFS + half * 64 + tid];
    __syncthreads();
    int e0 = off[0], cnt = off[64] - e0;
    const int* ptr = srow + (size_t)b * CAPB + e0;
    for (int s = tid; s < cnt; s += 256) sidx[s] = ptr[s];
    __syncthreads();

    int wid = tid >> 6, lane = tid & 63;
    int sg = lane >> 4, sl = lane & 15;
    const ushort4* hs4 = (const ushort4*)hs;     // row = 16 x ushort4 (128 B)
    #pragma unroll
    for (int k = 0; k < 4; ++k) {
        int n = k * 16 + wid * 4 + sg;           // node within half
        int g = b * BKN + half * 64 + n;
        if (g < NN) {
            float4 a0 = make_float4(0.f, 0.f, 0.f, 0.f);
            float4 a1 = make_float4(0.f, 0.f, 0.f, 0.f);
            float4 a2 = make_float4(0.f, 0.f, 0.f, 0.f);
            float4 a3 = make_float4(0.f, 0.f, 0.f, 0.f);
            bfacc(a0, hs4[(size_t)g * 16 + sl]);           // self loop
            int e = off[n] - e0, ee = off[n + 1] - e0;
            for (; e + 8 <= ee; e += 8) {
                int r0 = sidx[e + 0], r1 = sidx[e + 1];
                int r2 = sidx[e + 2], r3 = sidx[e + 3];
                int r4 = sidx[e + 4], r5 = sidx[e + 5];
                int r6 = sidx[e + 6], r7 = sidx[e + 7];
                ushort4 v0 = hs4[(size_t)r0 * 16 + sl];
                ushort4 v1 = hs4[(size_t)r1 * 16 + sl];
                ushort4 v2 = hs4[(size_t)r2 * 16 + sl];
                ushort4 v3 = hs4[(size_t)r3 * 16 + sl];
                ushort4 v4 = hs4[(size_t)r4 * 16 + sl];
                ushort4 v5 = hs4[(size_t)r5 * 16 + sl];
                ushort4 v6 = hs4[(size_t)r6 * 16 + sl];
                ushort4 v7 = hs4[(size_t)r7 * 16 + sl];
                bfacc(a0, v0); bfacc(a1, v1); bfacc(a2, v2); bfacc(a3, v3);
                bfacc(a0, v4); bfacc(a1, v5); bfacc(a2, v6); bfacc(a3, v7);
            }
            if (e + 4 <= ee) {
                int r0 = sidx[e + 0], r1 = sidx[e + 1];
                int r2 = sidx[e + 2], r3 = sidx[e + 3];
                ushort4 v0 = hs4[(size_t)r0 * 16 + sl];
                ushort4 v1 = hs4[(size_t)r1 * 16 + sl];
                ushort4 v2 = hs4[(size_t)r2 * 16 + sl];
                ushort4 v3 = hs4[(size_t)r3 * 16 + sl];
                bfacc(a0, v0); bfacc(a1, v1); bfacc(a2, v2); bfacc(a3, v3);
                e += 4;
            }
            for (; e < ee; ++e) {
                int r = sidx[e];
                bfacc(a0, hs4[(size_t)r * 16 + sl]);
            }
            float d = dinv[g];
            float4 bb = *(const float4*)(bias + sl * 4);
            float4 t;
            t.x = a0.x + a1.x + a2.x + a3.x;
            t.y = a0.y + a1.y + a2.y + a3.y;
            t.z = a0.z + a1.z + a2.z + a3.z;
            t.w = a0.w + a1.w + a2.w + a3.w;
            float4 o;
            o.x = fmaxf(fmaf(t.x, d, bb.x), 0.f);
            o.y = fmaxf(fmaf(t.y, d, bb.y), 0.f);
            o.z = fmaxf(fmaf(t.z, d, bb.z), 0.f);
            o.w = fmaxf(fmaf(t.w, d, bb.w), 0.f);
            ((float4*)out)[(size_t)g * 16 + sl] = o;
        }
    }
}

// ---------------- launch ----------------

extern "C" void kernel_launch(void* const* d_in, const int* in_sizes, int n_in,
                              void* d_out, int out_size, void* d_ws, size_t ws_size,
                              hipStream_t stream) {
    const float* x  = (const float*)d_in[0];
    const int* ei   = (const int*)d_in[1];      // [2, NE]
    const int* row  = ei;
    const int* col  = ei + NE;
    const float* W1 = (const float*)d_in[2];
    const float* b1 = (const float*)d_in[3];
    const float* W2 = (const float*)d_in[4];
    const float* b2 = (const float*)d_in[5];
    const float* Wc = (const float*)d_in[6];
    const float* bc = (const float*)d_in[7];
    float* out = (float*)d_out;

    char* ws = (char*)d_ws;
    size_t off = 0;
    auto alloc = [&](size_t bytes) {
        void* p = ws + off;
        off = (off + bytes + 255) & ~(size_t)255;
        return p;
    };
    int*   gcnt = (int*)alloc((size_t)NBK * 4);
    int*   offg = (int*)alloc((size_t)NBK * OFFS * 4);
    float* dinv = (float*)alloc((size_t)NN * 4);
    unsigned int* encs = (unsigned int*)alloc((size_t)NBK * CAPB * 4);   // 8 MB
    unsigned short* hsb = (unsigned short*)alloc((size_t)NN * NH * 2);   // bf16 table
    float* bufB = (float*)alloc((size_t)NN * NH * 4);

    const int GB = (NN + 63) / 64;               // 1563

    hipMemsetAsync(gcnt, 0, (size_t)NBK * 4, stream);
    bucket_scatter<<<NCHB, 256, 0, stream>>>(row, col, gcnt, encs);
    csr_sort<<<NBK, 256, 0, stream>>>(encs, gcnt, offg, dinv);

    // layer 1: hsb = bf16((x @ W1) * dinv) ; h1 = relu(dinv * agg + b1)
    gemm_tiled<NF, NH, 0><<<GB, 256, 0, stream>>>(x, W1, dinv, nullptr, hsb);
    aggregate_bucket<<<NBK * 2, 256, 0, stream>>>(hsb, (const int*)encs, offg, dinv, b1, bufB);
    // layer 2
    gemm_tiled<NH, NH, 0><<<GB, 256, 0, stream>>>(bufB, W2, dinv, nullptr, hsb);
    aggregate_bucket<<<NBK * 2, 256, 0, stream>>>(hsb, (const int*)encs, offg, dinv, b2, bufB);
    // classifier
    gemm_tiled<NH, NC, 1><<<GB, 256, 0, stream>>>(bufB, Wc, bc, out, nullptr);
}